// Round 4
// baseline (792.754 us; speedup 1.0000x reference)
//
#include <hip/hip_runtime.h>

// Output layout (flat): x_residual[2048*62*64], Sloss, dloss, S[2048*62*62]
#define XR_OFF 0
#define SL_OFF 8126464
#define DL_OFF 8126465
#define S_OFF  8126466

#define ALPHA_F 1e-4f
#define INV_SQRT310 0.05679618342470648f  // 1/sqrt(62*5)
#define INV_SQRT15  0.2581988897471611f   // 1/sqrt(3*5)

// LDS (floats), hand-packed: 13438 floats = 53752 B. 512-thr blocks -> 2 blocks/CU = 16 waves/CU.
#define L_SX 0        // 930 (+2 pad)  x[b] [t][v][f]
#define L_A  932      // 3844  tmpS -> S -> C1 = S*At           [u][v] stride 62
#define L_B  4776     // 3844  Sm -> expAt -> C2 = (2S^2-I)*At  [u][v] stride 62
#define L_C  8620     // 3968  z2 / sigmoid[62][64] / reduction scratch / gcn[62][64]
#define L_D  12588    // 850   smalls / G[62][12] / diag / sred
#define LDS_N 13438

// D-region: attention phase (dead before stage F)
#define D_SL   0      // 186  lhs[t][u] then s_lhs[v][3]
#define D_SR   186    // 186  U3rhs[v][t] then R3b[v][t]
#define D_SR2  372    // 186  s_rhs[s][v]
#define D_SY   558    // 15
#define D_PROD 573    // 9
#define D_SE   582    // 9
#define D_TAT  591    // 9
#define D_SCOL 600    // 62   1/colsum(tmpS)
// D-region: stage F (G overwrites attention smalls; DIAG/SRED beyond)
#define D_G    0      // 744 = [62][12]
#define D_DIAG 744    // 62
#define D_SRED 806    // 16

// Prep: transpose tw (o,c,t) -> twt (t,c,o); zero the two loss accumulators.
__global__ void prep_kernel(const float* __restrict__ tw, float* __restrict__ twt,
                            float* __restrict__ out) {
    int i = blockIdx.x * 256 + threadIdx.x;
    if (i < 12288) {
        int t = i >> 12, r = i & 4095, c = r >> 6, o = r & 63;
        twt[i] = tw[o * 192 + c * 3 + t];
    }
    if (i < 2) out[SL_OFF + i] = 0.f;
}

__launch_bounds__(512, 4)
__global__ void stgcn_kernel(
    const float* __restrict__ x,     const float* __restrict__ U1,
    const float* __restrict__ U2,    const float* __restrict__ U3,
    const float* __restrict__ be,    const float* __restrict__ Ve,
    const float* __restrict__ W1,    const float* __restrict__ W2,
    const float* __restrict__ W3,    const float* __restrict__ bs,
    const float* __restrict__ Vs,    const float* __restrict__ aF,
    const float* __restrict__ Theta, const float* __restrict__ twt,
    const float* __restrict__ tb,    const float* __restrict__ rw,
    const float* __restrict__ rb,    const float* __restrict__ gamma_,
    const float* __restrict__ beta_, float* __restrict__ out)
{
    __shared__ float lds[LDS_N];

    const int b   = blockIdx.x;
    const int tid = threadIdx.x;
    const int o   = tid & 63;
    const int q   = tid >> 6;            // wave 0..7
    const int nv  = (q < 6) ? 8 : 7;     // wave q owns v = q + 8j

    // persistent per-lane registers (all constant-indexed after unroll)
    float th[15];
    #pragma unroll
    for (int kf = 0; kf < 15; ++kf) th[kf] = Theta[kf * 64 + o];
    float rw5[5];
    #pragma unroll
    for (int f = 0; f < 5; ++f) rw5[f] = rw[o * 5 + f];
    const float rb_o = rb[o], tb_o = tb[o], gam = gamma_[o], bet = beta_[o];

    // ---- P0: load x[b] ----
    for (int i = tid; i < 930; i += 512) lds[L_SX + i] = x[(size_t)b * 930 + i];
    __syncthreads();

    // ---- temporal attention ----
    if (tid < 15) {                       // y[t][f] = sum_v x[t][v][f]*U1[v]
        int t = tid / 5, f = tid % 5;
        float s = 0.f;
        for (int v = 0; v < 62; ++v) s += lds[L_SX + t * 310 + v * 5 + f] * U1[v];
        lds[L_D + D_SY + tid] = s;
    }
    if (tid < 186) {                      // U3rhs[v][t] = sum_f U3[f]*x[t][v][f]
        int v = tid / 3, t = tid % 3;
        float s = 0.f;
        #pragma unroll
        for (int f = 0; f < 5; ++f) s += U3[f] * lds[L_SX + t * 310 + v * 5 + f];
        lds[L_D + D_SR + v * 3 + t] = s;
    }
    __syncthreads();
    if (tid < 186) {                      // lhs[t][u] = sum_f y[t][f]*U2[f][u]
        int t = tid / 62, u = tid % 62;
        float s = 0.f;
        #pragma unroll
        for (int f = 0; f < 5; ++f) s += lds[L_D + D_SY + t * 5 + f] * U2[f * 62 + u];
        lds[L_D + D_SL + t * 62 + u] = s;
    }
    __syncthreads();
    if (tid < 9) {                        // prod[t][u]
        int t = tid / 3, u = tid % 3;
        float s = 0.f;
        for (int v = 0; v < 62; ++v)
            s += lds[L_D + D_SL + t * 62 + v] * lds[L_D + D_SR + v * 3 + u];
        lds[L_D + D_PROD + tid] = s;
    }
    __syncthreads();
    if (tid < 9) {                        // E[t][u]
        int t = tid / 3, u = tid % 3;
        float s = 0.f;
        for (int ss = 0; ss < 3; ++ss) {
            float p = lds[L_D + D_PROD + ss * 3 + u] + be[ss * 3 + u];
            s += Ve[t * 3 + ss] * (1.f / (1.f + __expf(-p)));
        }
        lds[L_D + D_SE + tid] = s;
    }
    __syncthreads();
    if (tid < 3) {                        // softmax over t
        int u = tid;
        float e0v = lds[L_D + D_SE + u], e1v = lds[L_D + D_SE + 3 + u], e2v = lds[L_D + D_SE + 6 + u];
        float m = fmaxf(e0v, fmaxf(e1v, e2v));
        float e0 = __expf(e0v - m), e1 = __expf(e1v - m), e2 = __expf(e2v - m);
        float inv = 1.f / (e0 + e1 + e2);
        lds[L_D + D_TAT + u]     = e0 * inv;
        lds[L_D + D_TAT + 3 + u] = e1 * inv;
        lds[L_D + D_TAT + 6 + u] = e2 * inv;
    }
    __syncthreads();

    // ---- spatial attention front-end (x_TAt never materialized) ----
    if (tid < 310) {                      // z2[v][f] = sum_t x[t][v][f]*c[t] -> C[0:310]
        int v = tid / 5, f = tid % 5;
        float c0 = 0.f, c1 = 0.f, c2 = 0.f;
        #pragma unroll
        for (int u = 0; u < 3; ++u) {
            float w1u = W1[u];
            c0 += lds[L_D + D_TAT + 0 + u] * w1u;
            c1 += lds[L_D + D_TAT + 3 + u] * w1u;
            c2 += lds[L_D + D_TAT + 6 + u] * w1u;
        }
        float z = (lds[L_SX + v * 5 + f]       * c0 +
                   lds[L_SX + 310 + v * 5 + f] * c1 +
                   lds[L_SX + 620 + v * 5 + f] * c2) * INV_SQRT310;
        lds[L_C + v * 5 + f] = z;
    } else if (tid < 496) {               // R3b[v][t] = sum_f W3[f]*x[t][v][f]
        int i = tid - 310;
        int v = i / 3, t = i % 3;
        float s = 0.f;
        #pragma unroll
        for (int f = 0; f < 5; ++f) s += W3[f] * lds[L_SX + t * 310 + v * 5 + f];
        lds[L_D + D_SR + v * 3 + t] = s;
    }
    __syncthreads();
    if (tid < 186) {                      // s_lhs[v][s] = sum_f z2[v][f]*W2[f][s]
        int v = tid / 3, s3 = tid % 3;
        float s = 0.f;
        #pragma unroll
        for (int f = 0; f < 5; ++f) s += lds[L_C + v * 5 + f] * W2[f * 3 + s3];
        lds[L_D + D_SL + v * 3 + s3] = s;
    } else if (tid < 372) {               // s_rhs[s][v] = sum_t R3b[v][t]*tAt[t][s]/sqrt310
        int i = tid - 186;
        int s3 = i / 62, v = i % 62;
        float s = 0.f;
        #pragma unroll
        for (int t = 0; t < 3; ++t)
            s += lds[L_D + D_SR + v * 3 + t] * lds[L_D + D_TAT + t * 3 + s3];
        lds[L_D + D_SR2 + s3 * 62 + v] = s * INV_SQRT310;
    }
    __syncthreads();
    // sigmoid matrix [62][64] (cols 62,63 = 0) -> C
    for (int i = tid; i < 3968; i += 512) {
        int u = i >> 6, v = i & 63;
        float val = 0.f;
        if (v < 62) {
            float s = bs[u * 62 + v];
            #pragma unroll
            for (int t = 0; t < 3; ++t)
                s += lds[L_D + D_SL + u * 3 + t] * lds[L_D + D_SR2 + t * 62 + v];
            val = 1.f / (1.f + __expf(-s));
        }
        lds[L_C + i] = val;
    }
    __syncthreads();
    // Sm = Vs @ sig -> B (float4 over v), and tmpS -> A (disjoint buffers, same phase)
    for (int it = tid; it < 992; it += 512) {
        int u = it >> 4, v4 = (it & 15) << 2;
        const float* vr = Vs + u * 62;
        float sx_ = 0.f, sy_ = 0.f, sz_ = 0.f, sw_ = 0.f;
        for (int w = 0; w < 62; ++w) {
            float4 g4 = *(const float4*)&lds[L_C + (w << 6) + v4];
            float p = vr[w];
            sx_ += p * g4.x; sy_ += p * g4.y; sz_ += p * g4.z; sw_ += p * g4.w;
        }
        lds[L_B + u * 62 + v4]     = sx_;
        lds[L_B + u * 62 + v4 + 1] = sy_;
        if (v4 < 60) {
            lds[L_B + u * 62 + v4 + 2] = sz_;
            lds[L_B + u * 62 + v4 + 3] = sw_;
        }
    }
    for (int idx = tid; idx < 3844; idx += 512) {
        int i2 = idx / 62, j = idx - i2 * 62;
        float s = 0.f;
        #pragma unroll
        for (int f = 0; f < 5; ++f)
            s += fabsf(lds[L_SX + 310 + i2 * 5 + f] - lds[L_SX + 310 + j * 5 + f]) * aF[f];
        lds[L_A + idx] = __expf(fmaxf(s, 0.f));
    }
    __syncthreads();

    // ---- parallel column reductions: softmax(B) over u, colsum(A) ----
    {
        int seg = tid / 62, v = tid - seg * 62;
        int u0 = seg * 8, un = (seg == 7) ? 6 : 8;
        if (tid < 496) {   // Pa: partial colmax(B), partial colsum(A)
            float m = -1e30f, s = 0.f;
            for (int u = u0; u < u0 + un; ++u) {
                m = fmaxf(m, lds[L_B + u * 62 + v]);
                s += lds[L_A + u * 62 + v];
            }
            lds[L_C + tid]       = m;
            lds[L_C + 496 + tid] = s;
        } else if (tid < 501) {   // dloss partials (closed form)
            int f = tid - 496;
            float su = 0.f, sq = 0.f;
            for (int v2 = 0; v2 < 62; ++v2) {
                float xv = lds[L_SX + 310 + v2 * 5 + f];
                su += xv; sq += xv * xv;
            }
            lds[L_D + D_SRED + 8 + f] = 124.f * sq - 2.f * su * su;
        }
        __syncthreads();
        if (tid < 62) {    // Pb: combine -> mxfull, 1/colsum(A)
            float m = -1e30f, s = 0.f;
            #pragma unroll
            for (int sg = 0; sg < 8; ++sg) {
                m = fmaxf(m, lds[L_C + sg * 62 + tid]);
                s += lds[L_C + 496 + sg * 62 + tid];
            }
            lds[L_C + 992 + tid]    = m;
            lds[L_D + D_SCOL + tid] = 1.f / s;
        }
        __syncthreads();
        if (tid < 496) {   // Pc: exp(B-m) in place + partial colsum
            float m = lds[L_C + 992 + v];
            float s = 0.f;
            for (int u = u0; u < u0 + un; ++u) {
                float e = __expf(lds[L_B + u * 62 + v] - m);
                lds[L_B + u * 62 + v] = e;
                s += e;
            }
            lds[L_C + tid] = s;
        }
        __syncthreads();
        if (tid < 62) {    // Pd: 1/colsum(expAt) -> C[992+v]
            float s = 0.f;
            #pragma unroll
            for (int sg = 0; sg < 8; ++sg) s += lds[L_C + sg * 62 + tid];
            lds[L_C + 992 + tid] = 1.f / s;
        }
        __syncthreads();
    }

    // ---- transform: S out, Sloss, A<-C1, B<-C2, diag(At) ----
    float slp = 0.f;
    const size_t bo = (size_t)b * 3844;
    for (int idx = tid; idx < 3844; idx += 512) {
        int i2 = idx / 62, j = idx - i2 * 62;
        float sv = lds[L_A + idx] * lds[L_D + D_SCOL + j];
        out[S_OFF + bo + idx] = sv;
        slp += sv * sv;
        float At = lds[L_B + idx] * lds[L_C + 992 + j];
        if (i2 == j) lds[L_D + D_DIAG + i2] = At;
        lds[L_A + idx] = sv * At;                                         // C1
        lds[L_B + idx] = (2.f * sv * sv - ((i2 == j) ? 1.f : 0.f)) * At;  // C2
    }
    #pragma unroll
    for (int m = 32; m > 0; m >>= 1) slp += __shfl_down(slp, m, 64);
    if (o == 0) lds[L_D + D_SRED + q] = slp;
    __syncthreads();
    if (tid == 0) {
        float sl = 0.f;
        #pragma unroll
        for (int w = 0; w < 8; ++w) sl += lds[L_D + D_SRED + w];
        atomicAdd(out + SL_OFF, sl * (ALPHA_F / 2048.f));
        atomicAdd(out + DL_OFF, (lds[L_D + D_SRED + 8] + lds[L_D + D_SRED + 9] +
                                 lds[L_D + D_SRED + 10] + lds[L_D + D_SRED + 11] +
                                 lds[L_D + D_SRED + 12]) * ALPHA_F);
    }

    // ---- stage F: GCN + temporal conv ----
    float acc[8];
    #pragma unroll
    for (int j = 0; j < 8; ++j) acc[j] = 0.f;

    for (int t = 0; t < 3; ++t) {
        __syncthreads();
        // step1: G[v][12]: [0:5)=g1(f) = -sum_u C1[u][v]x[t][u][f]; [5:10)=g2(f) with C2
        if (tid < 310) {
            int v = tid / 5, f = tid % 5;
            float g1 = 0.f, g2 = 0.f;
            const float* xa = lds + L_SX + t * 310 + f;
            for (int u = 0; u < 62; ++u) {
                float xv = xa[u * 5];
                g1 -= lds[L_A + u * 62 + v] * xv;
                g2 += lds[L_B + u * 62 + v] * xv;
            }
            lds[L_D + D_G + v * 12 + f]     = g1;
            lds[L_D + D_G + v * 12 + 5 + f] = g2;
        }
        __syncthreads();
        // step2: gcn[v][o] = relu(diag*x.th[0:5] + G.th[5:15]) -> C[v][64]
        #pragma unroll
        for (int j = 0; j < 8; ++j) {
            if (j < nv) {
                int v = q + 8 * j;
                float4 r0 = *(const float4*)&lds[L_D + D_G + v * 12];
                float4 r1 = *(const float4*)&lds[L_D + D_G + v * 12 + 4];
                float r8 = lds[L_D + D_G + v * 12 + 8];
                float r9 = lds[L_D + D_G + v * 12 + 9];
                float dv = lds[L_D + D_DIAG + v];
                float s = 0.f;
                #pragma unroll
                for (int f = 0; f < 5; ++f)
                    s += dv * lds[L_SX + t * 310 + v * 5 + f] * th[f];
                s += r0.x * th[5] + r0.y * th[6] + r0.z * th[7] + r0.w * th[8];
                s += r1.x * th[9] + r1.y * th[10] + r1.z * th[11] + r1.w * th[12];
                s += r8 * th[13] + r9 * th[14];
                lds[L_C + v * 64 + o] = fmaxf(s, 0.f);
            }
        }
        __syncthreads();
        // step3: acc[j] += sum_c gcn[v][c]*tw[o][c][t]  (b128 broadcast gcn reads)
        const float* twtp = twt + t * 4096;
        for (int c4 = 0; c4 < 16; ++c4) {
            float w0 = twtp[(4 * c4 + 0) * 64 + o];
            float w1 = twtp[(4 * c4 + 1) * 64 + o];
            float w2 = twtp[(4 * c4 + 2) * 64 + o];
            float w3 = twtp[(4 * c4 + 3) * 64 + o];
            #pragma unroll
            for (int j = 0; j < 8; ++j) {
                if (j < nv) {
                    float4 g4 = *(const float4*)&lds[L_C + (q + 8 * j) * 64 + 4 * c4];
                    acc[j] += g4.x * w0 + g4.y * w1 + g4.z * w2 + g4.w * w3;
                }
            }
        }
        // no barrier here: next step1 touches only D_G (already consumed);
        // next step2's C-writes are fenced by the barrier after step1.
    }

    // ---- epilogue: residual + relu + LayerNorm over o ----
    #pragma unroll
    for (int j = 0; j < 8; ++j) {
        if (j < nv) {
            int v = q + 8 * j;
            float r = rb_o;
            #pragma unroll
            for (int f = 0; f < 5; ++f) r += lds[L_SX + v * 5 + f] * rw5[f];  // x[:,0]
            float z = r + (acc[j] + tb_o) * INV_SQRT15;
            z = fmaxf(z, 0.f);
            float s1 = z, s2 = z * z;
            #pragma unroll
            for (int m = 1; m < 64; m <<= 1) {
                s1 += __shfl_xor(s1, m, 64);
                s2 += __shfl_xor(s2, m, 64);
            }
            float mean = s1 * 0.015625f;
            float var  = s2 * 0.015625f - mean * mean;
            out[XR_OFF + (size_t)b * 3968 + v * 64 + o] =
                (z - mean) * rsqrtf(var + 1e-5f) * gam + bet;
        }
    }
}

extern "C" void kernel_launch(void* const* d_in, const int* in_sizes, int n_in,
                              void* d_out, int out_size, void* d_ws, size_t ws_size,
                              hipStream_t stream) {
    const float* x   = (const float*)d_in[0];
    const float* U1  = (const float*)d_in[1];
    const float* U2  = (const float*)d_in[2];
    const float* U3  = (const float*)d_in[3];
    const float* be  = (const float*)d_in[4];
    const float* Ve  = (const float*)d_in[5];
    const float* W1  = (const float*)d_in[6];
    const float* W2  = (const float*)d_in[7];
    const float* W3  = (const float*)d_in[8];
    const float* bs  = (const float*)d_in[9];
    const float* Vs  = (const float*)d_in[10];
    const float* a   = (const float*)d_in[11];
    const float* Th  = (const float*)d_in[12];
    const float* tw  = (const float*)d_in[13];
    const float* tb  = (const float*)d_in[14];
    const float* rw  = (const float*)d_in[15];
    const float* rb  = (const float*)d_in[16];
    const float* gm  = (const float*)d_in[17];
    const float* bt  = (const float*)d_in[18];
    float* out = (float*)d_out;
    float* twt = (float*)d_ws;  // 12288 floats

    prep_kernel<<<48, 256, 0, stream>>>(tw, twt, out);
    stgcn_kernel<<<2048, 512, 0, stream>>>(x, U1, U2, U3, be, Ve, W1, W2, W3,
                                           bs, Vs, a, Th, twt, tb, rw, rb, gm, bt, out);
}

// Round 5
// 535.905 us; speedup vs baseline: 1.4793x; 1.4793x over previous
//
#include <hip/hip_runtime.h>

// Output layout (flat): x_residual[2048*62*64], Sloss, dloss, S[2048*62*62]
#define XR_OFF 0
#define SL_OFF 8126464
#define DL_OFF 8126465
#define S_OFF  8126466

#define ALPHA_F 1e-4f
#define INV_SQRT310 0.05679618342470648f  // 1/sqrt(62*5)
#define INV_SQRT15  0.2581988897471611f   // 1/sqrt(3*5)

// LDS (floats): 14556 floats = 58224 B -> 2 blocks/CU at 512 thr = 16 waves/CU.
#define L_SX 0        // 932   x[b] [t][v][f]
#define L_A  932      // 3844  tmpS -> S -> C1 = S*At           [u][v] stride 62
#define L_B  4776     // 3844  Sm -> expAt -> C2 = (2S^2-I)*At  [u][v] stride 62
#define L_C  8620     // 3968  sigmoid[62][64] / reduction scratch / gcn[62][64]
#define L_TH 12588    // 960   Theta [kf15][o64]
#define L_D  13548    // 1008  smalls / G[15][62] / diag / sred
#define LDS_N 14556

// D-region: attention phase (dead before stage F)
#define D_SL   0      // 186  lhs[t][u] then s_lhs[v][3]
#define D_SR   186    // 186  U3rhs[v][t] then R3b[v][t]
#define D_SR2  372    // 186  s_rhs[s][v]
#define D_SY   558    // 15
#define D_PROD 573    // 9
#define D_SE   582    // 9
#define D_TAT  591    // 9
#define D_SCOL 600    // 62   1/colsum(tmpS)
// D-region: stage F (G overwrites attention smalls; DIAG/SRED beyond)
#define D_G    0      // 930 = [kf15][v62]
#define D_DIAG 930    // 62
#define D_SRED 992    // 16

// Prep: transpose tw (o,c,t) -> twt (t,c,o); zero the two loss accumulators.
__global__ void prep_kernel(const float* __restrict__ tw, float* __restrict__ twt,
                            float* __restrict__ out) {
    int i = blockIdx.x * 256 + threadIdx.x;
    if (i < 12288) {
        int t = i >> 12, r = i & 4095, c = r >> 6, o = r & 63;
        twt[i] = tw[o * 192 + c * 3 + t];
    }
    if (i < 2) out[SL_OFF + i] = 0.f;
}

__launch_bounds__(512, 2)
__global__ void stgcn_kernel(
    const float* __restrict__ x,     const float* __restrict__ U1,
    const float* __restrict__ U2,    const float* __restrict__ U3,
    const float* __restrict__ be,    const float* __restrict__ Ve,
    const float* __restrict__ W1,    const float* __restrict__ W2,
    const float* __restrict__ W3,    const float* __restrict__ bs,
    const float* __restrict__ Vs,    const float* __restrict__ aF,
    const float* __restrict__ Theta, const float* __restrict__ twt,
    const float* __restrict__ tb,    const float* __restrict__ rw,
    const float* __restrict__ rb,    const float* __restrict__ gamma_,
    const float* __restrict__ beta_, float* __restrict__ out)
{
    __shared__ float lds[LDS_N];

    const int b   = blockIdx.x;
    const int tid = threadIdx.x;
    const int o   = tid & 63;
    const int q   = tid >> 6;            // wave 0..7
    const int nv  = (q < 6) ? 8 : 7;     // wave q owns v = q + 8j

    // ---- P0: load x[b] and Theta ----
    for (int i = tid; i < 930; i += 512) lds[L_SX + i] = x[(size_t)b * 930 + i];
    if (tid < 480) {
        lds[L_TH + tid]       = Theta[tid];
        lds[L_TH + 480 + tid] = Theta[480 + tid];
    }
    __syncthreads();

    // ---- temporal attention ----
    if (tid < 15) {                       // y[t][f] = sum_v x[t][v][f]*U1[v]
        int t = tid / 5, f = tid % 5;
        float s = 0.f;
        for (int v = 0; v < 62; ++v) s += lds[L_SX + t * 310 + v * 5 + f] * U1[v];
        lds[L_D + D_SY + tid] = s;
    }
    if (tid < 186) {                      // U3rhs[v][t] = sum_f U3[f]*x[t][v][f]
        int v = tid / 3, t = tid % 3;
        float s = 0.f;
        #pragma unroll
        for (int f = 0; f < 5; ++f) s += U3[f] * lds[L_SX + t * 310 + v * 5 + f];
        lds[L_D + D_SR + v * 3 + t] = s;
    }
    __syncthreads();
    if (tid < 186) {                      // lhs[t][u] = sum_f y[t][f]*U2[f][u]
        int t = tid / 62, u = tid % 62;
        float s = 0.f;
        #pragma unroll
        for (int f = 0; f < 5; ++f) s += lds[L_D + D_SY + t * 5 + f] * U2[f * 62 + u];
        lds[L_D + D_SL + t * 62 + u] = s;
    }
    __syncthreads();
    if (tid < 9) {                        // prod[t][u]
        int t = tid / 3, u = tid % 3;
        float s = 0.f;
        for (int v = 0; v < 62; ++v)
            s += lds[L_D + D_SL + t * 62 + v] * lds[L_D + D_SR + v * 3 + u];
        lds[L_D + D_PROD + tid] = s;
    }
    __syncthreads();
    if (tid < 9) {                        // E[t][u]
        int t = tid / 3, u = tid % 3;
        float s = 0.f;
        for (int ss = 0; ss < 3; ++ss) {
            float p = lds[L_D + D_PROD + ss * 3 + u] + be[ss * 3 + u];
            s += Ve[t * 3 + ss] * (1.f / (1.f + __expf(-p)));
        }
        lds[L_D + D_SE + tid] = s;
    }
    __syncthreads();
    if (tid < 3) {                        // softmax over t
        int u = tid;
        float e0v = lds[L_D + D_SE + u], e1v = lds[L_D + D_SE + 3 + u], e2v = lds[L_D + D_SE + 6 + u];
        float m = fmaxf(e0v, fmaxf(e1v, e2v));
        float e0 = __expf(e0v - m), e1 = __expf(e1v - m), e2 = __expf(e2v - m);
        float inv = 1.f / (e0 + e1 + e2);
        lds[L_D + D_TAT + u]     = e0 * inv;
        lds[L_D + D_TAT + 3 + u] = e1 * inv;
        lds[L_D + D_TAT + 6 + u] = e2 * inv;
    }
    __syncthreads();

    // ---- spatial attention front-end (x_TAt never materialized) ----
    if (tid < 310) {                      // z2[v][f] -> C[0:310]
        int v = tid / 5, f = tid % 5;
        float c0 = 0.f, c1 = 0.f, c2 = 0.f;
        #pragma unroll
        for (int u = 0; u < 3; ++u) {
            float w1u = W1[u];
            c0 += lds[L_D + D_TAT + 0 + u] * w1u;
            c1 += lds[L_D + D_TAT + 3 + u] * w1u;
            c2 += lds[L_D + D_TAT + 6 + u] * w1u;
        }
        float z = (lds[L_SX + v * 5 + f]       * c0 +
                   lds[L_SX + 310 + v * 5 + f] * c1 +
                   lds[L_SX + 620 + v * 5 + f] * c2) * INV_SQRT310;
        lds[L_C + v * 5 + f] = z;
    } else if (tid < 496) {               // R3b[v][t] = sum_f W3[f]*x[t][v][f]
        int i = tid - 310;
        int v = i / 3, t = i % 3;
        float s = 0.f;
        #pragma unroll
        for (int f = 0; f < 5; ++f) s += W3[f] * lds[L_SX + t * 310 + v * 5 + f];
        lds[L_D + D_SR + v * 3 + t] = s;
    }
    __syncthreads();
    if (tid < 186) {                      // s_lhs[v][s] = sum_f z2[v][f]*W2[f][s]
        int v = tid / 3, s3 = tid % 3;
        float s = 0.f;
        #pragma unroll
        for (int f = 0; f < 5; ++f) s += lds[L_C + v * 5 + f] * W2[f * 3 + s3];
        lds[L_D + D_SL + v * 3 + s3] = s;
    } else if (tid < 372) {               // s_rhs[s][v] = sum_t R3b[v][t]*tAt[t][s]/sqrt310
        int i = tid - 186;
        int s3 = i / 62, v = i % 62;
        float s = 0.f;
        #pragma unroll
        for (int t = 0; t < 3; ++t)
            s += lds[L_D + D_SR + v * 3 + t] * lds[L_D + D_TAT + t * 3 + s3];
        lds[L_D + D_SR2 + s3 * 62 + v] = s * INV_SQRT310;
    }
    __syncthreads();
    // sigmoid matrix [62][64] (cols 62,63 = 0) -> C
    for (int i = tid; i < 3968; i += 512) {
        int u = i >> 6, v = i & 63;
        float val = 0.f;
        if (v < 62) {
            float s = bs[u * 62 + v];
            #pragma unroll
            for (int t = 0; t < 3; ++t)
                s += lds[L_D + D_SL + u * 3 + t] * lds[L_D + D_SR2 + t * 62 + v];
            val = 1.f / (1.f + __expf(-s));
        }
        lds[L_C + i] = val;
    }
    __syncthreads();
    // Sm = Vs @ sig -> B (float4 over v), and tmpS -> A (disjoint buffers, same phase)
    for (int it = tid; it < 992; it += 512) {
        int u = it >> 4, v4 = (it & 15) << 2;
        const float* vr = Vs + u * 62;
        float sx_ = 0.f, sy_ = 0.f, sz_ = 0.f, sw_ = 0.f;
        for (int w = 0; w < 62; ++w) {
            float4 g4 = *(const float4*)&lds[L_C + (w << 6) + v4];
            float p = vr[w];
            sx_ += p * g4.x; sy_ += p * g4.y; sz_ += p * g4.z; sw_ += p * g4.w;
        }
        lds[L_B + u * 62 + v4]     = sx_;
        lds[L_B + u * 62 + v4 + 1] = sy_;
        if (v4 < 60) {
            lds[L_B + u * 62 + v4 + 2] = sz_;
            lds[L_B + u * 62 + v4 + 3] = sw_;
        }
    }
    for (int idx = tid; idx < 3844; idx += 512) {
        int i2 = idx / 62, j = idx - i2 * 62;
        float s = 0.f;
        #pragma unroll
        for (int f = 0; f < 5; ++f)
            s += fabsf(lds[L_SX + 310 + i2 * 5 + f] - lds[L_SX + 310 + j * 5 + f]) * aF[f];
        lds[L_A + idx] = __expf(fmaxf(s, 0.f));
    }
    __syncthreads();

    // ---- parallel column reductions: softmax(B) over u, colsum(A) ----
    {
        int seg = tid / 62, v = tid - seg * 62;
        int u0 = seg * 8, un = (seg == 7) ? 6 : 8;
        if (tid < 496) {   // Pa: partial colmax(B), partial colsum(A)
            float m = -1e30f, s = 0.f;
            for (int u = u0; u < u0 + un; ++u) {
                m = fmaxf(m, lds[L_B + u * 62 + v]);
                s += lds[L_A + u * 62 + v];
            }
            lds[L_C + tid]       = m;
            lds[L_C + 496 + tid] = s;
        } else if (tid < 501) {   // dloss partials (closed form)
            int f = tid - 496;
            float su = 0.f, sq = 0.f;
            for (int v2 = 0; v2 < 62; ++v2) {
                float xv = lds[L_SX + 310 + v2 * 5 + f];
                su += xv; sq += xv * xv;
            }
            lds[L_D + D_SRED + 8 + f] = 124.f * sq - 2.f * su * su;
        }
        __syncthreads();
        if (tid < 62) {    // Pb: combine -> colmax, 1/colsum(A)
            float m = -1e30f, s = 0.f;
            #pragma unroll
            for (int sg = 0; sg < 8; ++sg) {
                m = fmaxf(m, lds[L_C + sg * 62 + tid]);
                s += lds[L_C + 496 + sg * 62 + tid];
            }
            lds[L_C + 992 + tid]    = m;
            lds[L_D + D_SCOL + tid] = 1.f / s;
        }
        __syncthreads();
        if (tid < 496) {   // Pc: exp(B-m) in place + partial colsum
            float m = lds[L_C + 992 + v];
            float s = 0.f;
            for (int u = u0; u < u0 + un; ++u) {
                float e = __expf(lds[L_B + u * 62 + v] - m);
                lds[L_B + u * 62 + v] = e;
                s += e;
            }
            lds[L_C + tid] = s;
        }
        __syncthreads();
        if (tid < 62) {    // Pd: 1/colsum(expAt)
            float s = 0.f;
            #pragma unroll
            for (int sg = 0; sg < 8; ++sg) s += lds[L_C + sg * 62 + tid];
            lds[L_C + 992 + tid] = 1.f / s;
        }
        __syncthreads();
    }

    // ---- transform: S out, Sloss, A<-C1, B<-C2, diag(At) ----
    float slp = 0.f;
    const size_t bo = (size_t)b * 3844;
    for (int idx = tid; idx < 3844; idx += 512) {
        int i2 = idx / 62, j = idx - i2 * 62;
        float sv = lds[L_A + idx] * lds[L_D + D_SCOL + j];
        out[S_OFF + bo + idx] = sv;
        slp += sv * sv;
        float At = lds[L_B + idx] * lds[L_C + 992 + j];
        if (i2 == j) lds[L_D + D_DIAG + i2] = At;
        lds[L_A + idx] = sv * At;                                         // C1
        lds[L_B + idx] = (2.f * sv * sv - ((i2 == j) ? 1.f : 0.f)) * At;  // C2
    }
    #pragma unroll
    for (int m = 32; m > 0; m >>= 1) slp += __shfl_down(slp, m, 64);
    if (o == 0) lds[L_D + D_SRED + q] = slp;
    __syncthreads();
    if (tid == 0) {
        float sl = 0.f;
        #pragma unroll
        for (int w = 0; w < 8; ++w) sl += lds[L_D + D_SRED + w];
        atomicAdd(out + SL_OFF, sl * (ALPHA_F / 2048.f));
        atomicAdd(out + DL_OFF, (lds[L_D + D_SRED + 8] + lds[L_D + D_SRED + 9] +
                                 lds[L_D + D_SRED + 10] + lds[L_D + D_SRED + 11] +
                                 lds[L_D + D_SRED + 12]) * ALPHA_F);
    }

    // ---- stage F: GCN + temporal conv ----
    float acc[8];
    #pragma unroll
    for (int j = 0; j < 8; ++j) acc[j] = 0.f;

    for (int t = 0; t < 3; ++t) {
        __syncthreads();
        // step1: G[kf][v]; kf = f (g0 = diag*x), 5+f (g1 = -C1^T x), 10+f (g2 = +C2^T x)
        if (tid < 310) {
            int f = tid / 62, v = tid - f * 62;
            float g0 = lds[L_D + D_DIAG + v] * lds[L_SX + t * 310 + v * 5 + f];
            float g1 = 0.f, g2 = 0.f;
            const float* xa = lds + L_SX + t * 310 + f;
            const float* Ac = lds + L_A + v;
            const float* Bc = lds + L_B + v;
            for (int u = 0; u < 62; ++u) {
                float xv = xa[u * 5];
                g1 -= Ac[u * 62] * xv;
                g2 += Bc[u * 62] * xv;
            }
            lds[L_D + D_G + f * 62 + v]        = g0;
            lds[L_D + D_G + (5 + f) * 62 + v]  = g1;
            lds[L_D + D_G + (10 + f) * 62 + v] = g2;
        }
        __syncthreads();
        // step2: gcn[v][o] = relu(sum_kf G[kf][v]*Theta[kf][o]) -> C[v][64]; kf-outer, tiny window
        {
            float s[8];
            #pragma unroll
            for (int j = 0; j < 8; ++j) s[j] = 0.f;
            #pragma unroll
            for (int kf = 0; kf < 15; ++kf) {
                float tha = lds[L_TH + kf * 64 + o];
                #pragma unroll
                for (int j = 0; j < 8; ++j) {
                    if (j < nv) s[j] += lds[L_D + D_G + kf * 62 + (q + 8 * j)] * tha;
                }
            }
            #pragma unroll
            for (int j = 0; j < 8; ++j)
                if (j < nv) lds[L_C + (q + 8 * j) * 64 + o] = fmaxf(s[j], 0.f);
        }
        __syncthreads();
        // step3: acc[j] += sum_c gcn[v][c]*tw[o][c][t]  (broadcast b128 gcn reads)
        const float* twtp = twt + t * 4096;
        #pragma unroll 2
        for (int c4 = 0; c4 < 16; ++c4) {
            float w0 = twtp[(4 * c4 + 0) * 64 + o];
            float w1 = twtp[(4 * c4 + 1) * 64 + o];
            float w2 = twtp[(4 * c4 + 2) * 64 + o];
            float w3 = twtp[(4 * c4 + 3) * 64 + o];
            #pragma unroll
            for (int j = 0; j < 8; ++j) {
                if (j < nv) {
                    float4 g4 = *(const float4*)&lds[L_C + (q + 8 * j) * 64 + 4 * c4];
                    acc[j] += g4.x * w0 + g4.y * w1 + g4.z * w2 + g4.w * w3;
                }
            }
        }
    }

    // ---- epilogue: residual + relu + LayerNorm over o (params loaded here, L1-hot) ----
    const float rb_o = rb[o], tb_o = tb[o], gam = gamma_[o], bet = beta_[o];
    #pragma unroll
    for (int j = 0; j < 8; ++j) {
        if (j < nv) {
            int v = q + 8 * j;
            float r = rb_o;
            #pragma unroll
            for (int f = 0; f < 5; ++f) r += lds[L_SX + v * 5 + f] * rw[o * 5 + f];  // x[:,0]
            float z = r + (acc[j] + tb_o) * INV_SQRT15;
            z = fmaxf(z, 0.f);
            float s1 = z, s2 = z * z;
            #pragma unroll
            for (int m = 1; m < 64; m <<= 1) {
                s1 += __shfl_xor(s1, m, 64);
                s2 += __shfl_xor(s2, m, 64);
            }
            float mean = s1 * 0.015625f;
            float var  = s2 * 0.015625f - mean * mean;
            out[XR_OFF + (size_t)b * 3968 + v * 64 + o] =
                (z - mean) * rsqrtf(var + 1e-5f) * gam + bet;
        }
    }
}

extern "C" void kernel_launch(void* const* d_in, const int* in_sizes, int n_in,
                              void* d_out, int out_size, void* d_ws, size_t ws_size,
                              hipStream_t stream) {
    const float* x   = (const float*)d_in[0];
    const float* U1  = (const float*)d_in[1];
    const float* U2  = (const float*)d_in[2];
    const float* U3  = (const float*)d_in[3];
    const float* be  = (const float*)d_in[4];
    const float* Ve  = (const float*)d_in[5];
    const float* W1  = (const float*)d_in[6];
    const float* W2  = (const float*)d_in[7];
    const float* W3  = (const float*)d_in[8];
    const float* bs  = (const float*)d_in[9];
    const float* Vs  = (const float*)d_in[10];
    const float* a   = (const float*)d_in[11];
    const float* Th  = (const float*)d_in[12];
    const float* tw  = (const float*)d_in[13];
    const float* tb  = (const float*)d_in[14];
    const float* rw  = (const float*)d_in[15];
    const float* rb  = (const float*)d_in[16];
    const float* gm  = (const float*)d_in[17];
    const float* bt  = (const float*)d_in[18];
    float* out = (float*)d_out;
    float* twt = (float*)d_ws;  // 12288 floats

    prep_kernel<<<48, 256, 0, stream>>>(tw, twt, out);
    stgcn_kernel<<<2048, 512, 0, stream>>>(x, U1, U2, U3, be, Ve, W1, W2, W3,
                                           bs, Vs, a, Th, twt, tb, rw, rb, gm, bt, out);
}